// Round 1
// baseline (380.095 us; speedup 1.0000x reference)
//
#include <hip/hip_runtime.h>
#include <cstddef>

#define H_    512
#define W_    512
#define NIMG  96           // 32 batch * 3 channels
#define PD_   16           // pad = KS/2
#define TY    64           // output rows per band (was 128): 2x blocks for occupancy
#define NROWS (TY + 31)    // 95 padded rows per band

// one DPP scan step: x += dpp_shifted(x); out-of-range lanes contribute 0
template <int CTRL, int RMASK>
__device__ __forceinline__ float dpp_add(float x) {
    int t = __builtin_amdgcn_update_dpp(0, __float_as_int(x), CTRL, RMASK, 0xf, true);
    return x + __int_as_float(t);
}

// wave64 inclusive prefix sum, pure VALU (6 dpp-adds)
__device__ __forceinline__ float wave_incl_scan(float x) {
    x = dpp_add<0x111, 0xf>(x);   // row_shr:1
    x = dpp_add<0x112, 0xf>(x);   // row_shr:2
    x = dpp_add<0x114, 0xf>(x);   // row_shr:4
    x = dpp_add<0x118, 0xf>(x);   // row_shr:8
    x = dpp_add<0x142, 0xa>(x);   // row_bcast:15 -> rows 1,3
    x = dpp_add<0x143, 0xc>(x);   // row_bcast:31 -> rows 2,3
    return x;
}

// TWO independent 32-lane inclusive scans (lanes 0-31 | lanes 32-63), 5 dpp-adds.
// Used to scan tail-g (low half) and tail-g^2 (high half) in ONE pass.
__device__ __forceinline__ float half_scan(float x) {
    x = dpp_add<0x111, 0xf>(x);
    x = dpp_add<0x112, 0xf>(x);
    x = dpp_add<0x114, 0xf>(x);
    x = dpp_add<0x118, 0xf>(x);
    x = dpp_add<0x142, 0xa>(x);   // row_bcast:15 within each 32-half only
    return x;
}

__device__ __forceinline__ float bcast63(float x) {
    return __int_as_float(__builtin_amdgcn_readlane(__float_as_int(x), 63));
}
__device__ __forceinline__ float bperm(int addr, float v) {
    return __int_as_float(__builtin_amdgcn_ds_bpermute(addr, __float_as_int(v)));
}

// Wave-autonomous: each wave owns a 64-col x TY-row strip. No __syncthreads.
// histq lives in LDS (thread-private slots, 2-way bank alias = free) to cut
// VGPRs; histg stays in registers (static idx via full unroll).
// NOTE: every cross-lane op executed unconditionally (full exec mask).
__global__ void __launch_bounds__(256, 5)
localnorm_kernel(const float* __restrict__ xin, float* __restrict__ out)
{
    __shared__ float hq_lds[32 * 256];      // 32 KB: [slot][tid]

    const int tid  = threadIdx.x;
    const int lane = tid & 63;
    const int wv   = tid >> 6;

    const int c0   = blockIdx.x * 256 + wv * 64;  // wave's first output col
    const int row0 = blockIdx.y * TY;
    const int img  = blockIdx.z;

    const float* __restrict__ src = xin + (size_t)img * (H_ * W_);
    float* __restrict__ dst = out + (size_t)img * (H_ * W_) + (size_t)row0 * W_ + c0;
    const float* __restrict__ xptr = src + (size_t)row0 * W_ + c0 + lane;  // x reload base

    // zero own history slots (thread-private -> no barrier needed)
#pragma unroll
    for (int s = 0; s < 32; ++s) hq_lds[s * 256 + tid] = 0.f;

    // padded col -> reflected original col (row-invariant)
    int pcm = c0 - PD_ + lane;                     // main: padded idx = lane
    const int ocm = (pcm < 0) ? -pcm : ((pcm > W_ - 1) ? 2 * (W_ - 1) - pcm : pcm);
    int pct = c0 - PD_ + 64 + (lane & 31);         // tail: both halves load same 31 cols
    const int oct = (pct > W_ - 1) ? 2 * (W_ - 1) - pct : pct;
    const bool lo32 = lane < 32;

    // precomputed ds_bpermute byte addresses (replaces per-call shfl addr math)
    const int A_dn  = ((lane + 31) & 63) << 2;     // S[lane+31]   (used lanes <= 32)
    const int A_u33 = ((lane - 33) & 63) << 2;     // SBg[lane-33] (used lanes >= 33)
    const int A_u1  = ((lane - 1)  & 63) << 2;     // SBq[lane-33] = packed[lane-1]

    auto rowbase = [&](int p) {
        int r = row0 + p - PD_;
        r = (r < 0) ? -r : ((r > H_ - 1) ? 2 * (H_ - 1) - r : r);
        return src + (size_t)r * W_;
    };

    // 4-deep register prefetch ring for row loads
    float gr[4], gtr[4];
#pragma unroll
    for (int p = 0; p < 4; ++p) {
        const float* rp = rowbase(p);
        gr[p]  = rp[ocm];
        gtr[p] = rp[oct];
    }

    // 32-deep rolling history of horizontal g-sums (registers, static idx)
    float histg[32];
#pragma unroll
    for (int k = 0; k < 32; ++k) histg[k] = 0.f;
    float vg = 0.f, vq = 0.f;                      // vertical rolling sums

    auto step = [&](int p, int gslot, int hslot, bool doOut, int i) {
        float g = gr[gslot], gt = gtr[gslot];
        {   // prefetch row p+4 into the slot just freed (clamped; dup loads hit L1)
            int pn = p + 4; if (pn > NROWS - 1) pn = NROWS - 1;
            const float* rp = rowbase(pn);
            gr[gslot]  = rp[ocm];
            gtr[gslot] = rp[oct];
        }
        float q = g * g;
        float t = lo32 ? gt : gt * gt;             // pack: lo half = tail g, hi half = tail g^2

        // scans: main g (6), main q (6), packed tail (5) -> 17 fused dpp-adds
        float sag = wave_incl_scan(g);
        float saq = wave_incl_scan(q);
        float sbt = half_scan(t);

        // hsum[lane] = S[lane+31] - S[lane-1] over the 95 padded values
        float sa63g = bcast63(sag), sa63q = bcast63(saq);
        float dng = bperm(A_dn, sag);              // S[lane+31], lanes <= 32
        float dnq = bperm(A_dn, saq);
        float ubg = bperm(A_u33, sbt);             // SBg[lane-33], lanes >= 33
        float ubq = bperm(A_u1,  sbt);             // SBq[lane-33] = sbt[lane-1]
        float slog = sag - g, sloq = saq - q;      // S[lane-1] == exclusive scan
        float shig = (lane <= 32) ? dng : (sa63g + ubg);
        float shiq = (lane <= 32) ? dnq : (sa63q + ubq);
        float hg = shig - slog;
        float hq = shiq - sloq;

        // vertical rolling 32-row window; hq history in LDS (thread-private slot)
        vg += hg - histg[hslot]; histg[hslot] = hg;
        float oq = hq_lds[hslot * 256 + tid];
        vq += hq - oq;
        hq_lds[hslot * 256 + tid] = hq;

        if (doOut) {
            float xv = xptr[(size_t)i * W_];       // x reload: L1/L2 hit (row touched 16 steps ago)
            float mg = vg * (1.f / 1024.f);
            float mq = vq * (1.f / 1024.f);
            float sd = sqrtf(fabsf(mq - mg * mg)) + 1e-10f;
            float r  = __fdividef(xv - mg, sd);
            r = fminf(fmaxf(r, -6.f), 6.f);
            dst[(size_t)i * W_ + lane] = r;
        }
    };

    // prologue: padded rows 0..30 (fills vertical window)
#pragma unroll
    for (int p = 0; p < 31; ++p)
        step(p, p & 3, p & 31, false, 0);

    // main: padded rows 31..94 -> output rows 0..63
    for (int pb = 31; pb < NROWS; pb += 32) {      // pb = 31,63 (pb % 32 == 31)
#pragma unroll
        for (int k = 0; k < 32; ++k) {
            step(pb + k, (k + 3) & 3, (k + 31) & 31, true, pb + k - 31);
        }
    }
}

extern "C" void kernel_launch(void* const* d_in, const int* in_sizes, int n_in,
                              void* d_out, int out_size, void* d_ws, size_t ws_size,
                              hipStream_t stream) {
    (void)in_sizes; (void)n_in; (void)d_ws; (void)ws_size; (void)out_size;
    const float* x = (const float*)d_in[0];
    float* o = (float*)d_out;
    dim3 grid(W_ / 256, H_ / TY, NIMG);   // 2 x 8 x 96 = 1536 blocks, 6/CU
    localnorm_kernel<<<grid, dim3(256), 0, stream>>>(x, o);
}

// Round 2
// 295.200 us; speedup vs baseline: 1.2876x; 1.2876x over previous
//
#include <hip/hip_runtime.h>
#include <cstddef>

#define H_    512
#define W_    512
#define NIMG  96           // 32 batch * 3 channels
#define PD_   16           // pad = KS/2
#define TY    64           // output rows per band
#define NROWS (TY + 31)    // 95 padded rows per band

// one DPP scan step: x += dpp_shifted(x); out-of-range lanes contribute 0
template <int CTRL, int RMASK>
__device__ __forceinline__ float dpp_add(float x) {
    int t = __builtin_amdgcn_update_dpp(0, __float_as_int(x), CTRL, RMASK, 0xf, true);
    return x + __int_as_float(t);
}

// wave64 inclusive prefix sum, pure VALU (6 dpp-adds)
__device__ __forceinline__ float wave_incl_scan(float x) {
    x = dpp_add<0x111, 0xf>(x);   // row_shr:1
    x = dpp_add<0x112, 0xf>(x);   // row_shr:2
    x = dpp_add<0x114, 0xf>(x);   // row_shr:4
    x = dpp_add<0x118, 0xf>(x);   // row_shr:8
    x = dpp_add<0x142, 0xa>(x);   // row_bcast:15 -> rows 1,3
    x = dpp_add<0x143, 0xc>(x);   // row_bcast:31 -> rows 2,3
    return x;
}

// TWO independent 32-lane inclusive scans (lanes 0-31 | 32-63), 5 dpp-adds.
// lo half scans tail-Sx, hi half scans tail-Sx^2 in ONE pass.
__device__ __forceinline__ float half_scan(float x) {
    x = dpp_add<0x111, 0xf>(x);
    x = dpp_add<0x112, 0xf>(x);
    x = dpp_add<0x114, 0xf>(x);
    x = dpp_add<0x118, 0xf>(x);
    x = dpp_add<0x142, 0xa>(x);   // row_bcast:15 within each 32-half only
    return x;
}

__device__ __forceinline__ float bcast63(float x) {
    return __int_as_float(__builtin_amdgcn_readlane(__float_as_int(x), 63));
}
__device__ __forceinline__ float bperm(int addr, float v) {
    return __int_as_float(__builtin_amdgcn_ds_bpermute(addr, __float_as_int(v)));
}

// VERTICAL-FIRST localnorm: each lane holds rolling vertical sums of its own
// padded column (main col + packed tail col). Horizontal 32-window runs on the
// vertical sums -> scans only on OUTPUT rows (64/band, not 95), and NO 32-deep
// register history (old rows re-loaded from global: self-re-read, L1/L2-warm).
// Wave-autonomous: no __syncthreads, no LDS. All cross-lane ops under full exec.
__global__ void __launch_bounds__(256, 6)
localnorm_kernel(const float* __restrict__ xin, float* __restrict__ out)
{
    const int tid  = threadIdx.x;
    const int lane = tid & 63;
    const int wv   = tid >> 6;

    const int c0   = blockIdx.x * 256 + wv * 64;  // wave's first output col
    const int row0 = blockIdx.y * TY;
    const int img  = blockIdx.z;

    const float* __restrict__ src = xin + (size_t)img * (H_ * W_);
    float* __restrict__ dst = out + (size_t)img * (H_ * W_) + (size_t)row0 * W_ + c0 + lane;
    const float* __restrict__ xp = src + (size_t)row0 * W_ + c0 + lane;  // x reload base

    // padded col -> reflected original col (row-invariant)
    int pcm = c0 - PD_ + lane;                     // main: padded idx = lane
    const int ocm = (pcm < 0) ? -pcm : ((pcm > W_ - 1) ? 2 * (W_ - 1) - pcm : pcm);
    int pct = c0 - PD_ + 64 + (lane & 31);         // tail: both halves load same col
    const int oct = (pct > W_ - 1) ? 2 * (W_ - 1) - pct : pct;
    const bool lo32 = lane < 32;

    // precomputed ds_bpermute byte addresses
    const int A_dn  = ((lane + 31) & 63) << 2;     // S[lane+31]    (used lanes <= 32)
    const int A_u33 = ((lane - 33) & 63) << 2;     // SBg[lane-33]  (used lanes >= 33)
    const int A_u1  = ((lane - 1)  & 63) << 2;     // SBq[lane-33] = packed[lane-1]

    auto rowbase = [&](int p) {
        int r = row0 + p - PD_;
        r = (r < 0) ? -r : ((r > H_ - 1) ? 2 * (H_ - 1) - r : r);
        return src + (size_t)r * W_;
    };

    // 4-deep prefetch ring for the NEW-row stream
    float gr[4], gtr[4];
#pragma unroll
    for (int p = 0; p < 4; ++p) {
        const float* rp = rowbase(p);
        gr[p]  = rp[ocm];
        gtr[p] = rp[oct];
    }

    // vertical rolling sums (the ONLY persistent state besides rings)
    float vmg = 0.f, vmq = 0.f, vt = 0.f;

    // prologue: padded rows 0..30 -> accumulate only, NO scans
#pragma unroll
    for (int p = 0; p < 31; ++p) {
        float g = gr[p & 3], gt = gtr[p & 3];
        {   int pn = p + 4;                        // max 34 < NROWS, no clamp needed
            const float* rp = rowbase(pn);
            gr[p & 3]  = rp[ocm];
            gtr[p & 3] = rp[oct];
        }
        vmg += g;
        vmq += g * g;
        vt  += lo32 ? gt : gt * gt;
    }

    // 2-deep ring for the OLD-row stream (rows read 32 steps ago; L1/L2-warm)
    float og[2], ogt[2];
#pragma unroll
    for (int p = 0; p < 2; ++p) {
        const float* rp = rowbase(p);
        og[p]  = rp[ocm];
        ogt[p] = rp[oct];
    }

    // one full step: add padded row i+31, subtract padded row i-1 (if sub),
    // horizontal-scan the vertical sums, emit output row i.
    auto step = [&](int i, bool sub) {
        const int p = i + 31;
        float g = gr[p & 3], gt = gtr[p & 3];
        {   int pn = p + 4; if (pn > NROWS - 1) pn = NROWS - 1;
            const float* rp = rowbase(pn);
            gr[p & 3]  = rp[ocm];
            gtr[p & 3] = rp[oct];
        }
        float o = og[(i - 1) & 1], ot = ogt[(i - 1) & 1];   // padded row i-1
        {   int on = i + 1; if (on > TY - 2) on = TY - 2;    // old rows end at 62
            const float* rp = rowbase(on);
            og[(i + 1) & 1]  = rp[ocm];
            ogt[(i + 1) & 1] = rp[oct];
        }
        if (sub) {
            vmg += g - o;
            vmq += g * g - o * o;
            vt  += lo32 ? (gt - ot) : (gt * gt - ot * ot);
        } else {
            vmg += g;
            vmq += g * g;
            vt  += lo32 ? gt : gt * gt;
        }

        // horizontal 32-window: hsum[c] = S[c+31] - S[c-1] over 95 padded cols
        float sag = wave_incl_scan(vmg);
        float saq = wave_incl_scan(vmq);
        float sbt = half_scan(vt);
        float sa63g = bcast63(sag), sa63q = bcast63(saq);
        float dng = bperm(A_dn, sag);              // S[lane+31], lanes <= 32
        float dnq = bperm(A_dn, saq);
        float ubg = bperm(A_u33, sbt);             // tail-Sx prefix, lanes >= 33
        float ubq = bperm(A_u1,  sbt);             // tail-Sx2 prefix, lanes >= 33
        float slog = sag - vmg, sloq = saq - vmq;  // exclusive scan = S[lane-1]
        float shig = (lane <= 32) ? dng : (sa63g + ubg);
        float shiq = (lane <= 32) ? dnq : (sa63q + ubq);
        float sg = shig - slog;                    // 32x32 box sum of x
        float sq = shiq - sloq;                    // 32x32 box sum of x^2

        float xv = xp[(size_t)i * W_];             // center x: row read 15 steps ago (L2-warm)
        float mg = sg * (1.f / 1024.f);
        float mq = sq * (1.f / 1024.f);
        float sd = sqrtf(fabsf(mq - mg * mg)) + 1e-10f;
        float r  = __fdividef(xv - mg, sd);
        r = fminf(fmaxf(r, -6.f), 6.f);
        dst[(size_t)i * W_] = r;
    };

    // main: output rows 0..63 (i=0 has no row to subtract: window fills to 32)
    step(0, false);
#pragma unroll
    for (int k = 1; k < 32; ++k) step(k, true);
#pragma unroll
    for (int k = 32; k < 64; ++k) step(k, true);
}

extern "C" void kernel_launch(void* const* d_in, const int* in_sizes, int n_in,
                              void* d_out, int out_size, void* d_ws, size_t ws_size,
                              hipStream_t stream) {
    (void)in_sizes; (void)n_in; (void)d_ws; (void)ws_size; (void)out_size;
    const float* x = (const float*)d_in[0];
    float* o = (float*)d_out;
    dim3 grid(W_ / 256, H_ / TY, NIMG);   // 2 x 8 x 96 = 1536 blocks, 6/CU
    localnorm_kernel<<<grid, dim3(256), 0, stream>>>(x, o);
}

// Round 3
// 220.505 us; speedup vs baseline: 1.7237x; 1.3387x over previous
//
#include <hip/hip_runtime.h>
#include <cstddef>
#include <cstdint>

#define H_    512
#define W_    512
#define NIMG  96           // 32 batch * 3 channels
#define PD_   16           // pad = KS/2
#define TY    64           // output rows per band
#define NROWS (TY + 31)    // 95 padded rows per band

// one DPP scan step: x += dpp_shifted(x); out-of-range lanes contribute 0
template <int CTRL, int RMASK>
__device__ __forceinline__ float dpp_add(float x) {
    int t = __builtin_amdgcn_update_dpp(0, __float_as_int(x), CTRL, RMASK, 0xf, true);
    return x + __int_as_float(t);
}

// wave64 inclusive prefix sum, pure VALU (6 dpp-adds)
__device__ __forceinline__ float wave_incl_scan(float x) {
    x = dpp_add<0x111, 0xf>(x);   // row_shr:1
    x = dpp_add<0x112, 0xf>(x);   // row_shr:2
    x = dpp_add<0x114, 0xf>(x);   // row_shr:4
    x = dpp_add<0x118, 0xf>(x);   // row_shr:8
    x = dpp_add<0x142, 0xa>(x);   // row_bcast:15 -> rows 1,3
    x = dpp_add<0x143, 0xc>(x);   // row_bcast:31 -> rows 2,3
    return x;
}

// TWO independent 32-lane inclusive scans (lanes 0-31 | 32-63), 5 dpp-adds.
// lo half scans tail-Sx, hi half scans tail-Sx^2 in ONE pass.
__device__ __forceinline__ float half_scan(float x) {
    x = dpp_add<0x111, 0xf>(x);
    x = dpp_add<0x112, 0xf>(x);
    x = dpp_add<0x114, 0xf>(x);
    x = dpp_add<0x118, 0xf>(x);
    x = dpp_add<0x142, 0xa>(x);   // row_bcast:15 within each 32-half only
    return x;
}

__device__ __forceinline__ float bcast63(float x) {
    return __int_as_float(__builtin_amdgcn_readlane(__float_as_int(x), 63));
}
__device__ __forceinline__ float bperm(int addr, float v) {
    return __int_as_float(__builtin_amdgcn_ds_bpermute(addr, __float_as_int(v)));
}

// round-to-nearest-even bf16, returned as f32 bits with low 16 zeroed
// (value usable directly as float AND as the high half of a packed dword)
__device__ __forceinline__ uint32_t rne_bf16_hi(float f) {
    uint32_t u = __float_as_uint(f);
    return (u + 0x7fffu + ((u >> 16) & 1u)) & 0xffff0000u;
}

// VERTICAL-FIRST localnorm, register history at bf16:
// each lane keeps rolling vertical sums of its padded column (main + packed
// tail). The 32-deep subtract history is ONE dword/slot: bf16(g)|bf16(gt).
// Added and subtracted values are the SAME rounded values -> exact rolling
// cancellation, no drift. Center x is f32 via a 4-deep prefetched global
// re-read ring (11-step reuse distance -> L2-warm). 3 loads/step, all
// consumed >=4 steps after issue (no vmcnt drains). No LDS, no barriers.
__global__ void __launch_bounds__(256, 4)
localnorm_kernel(const float* __restrict__ xin, float* __restrict__ out)
{
    const int tid  = threadIdx.x;
    const int lane = tid & 63;
    const int wv   = tid >> 6;

    const int c0   = blockIdx.x * 256 + wv * 64;  // wave's first output col
    const int row0 = blockIdx.y * TY;
    const int img  = blockIdx.z;

    const float* __restrict__ src = xin + (size_t)img * (H_ * W_);
    float* __restrict__ dst = out + (size_t)img * (H_ * W_) + (size_t)row0 * W_ + c0 + lane;
    const float* __restrict__ xp = src + (size_t)row0 * W_ + c0 + lane;  // x reload base

    // padded col -> reflected original col (row-invariant)
    int pcm = c0 - PD_ + lane;                     // main: padded idx = lane
    const int ocm = (pcm < 0) ? -pcm : ((pcm > W_ - 1) ? 2 * (W_ - 1) - pcm : pcm);
    int pct = c0 - PD_ + 64 + (lane & 31);         // tail: both halves load same col
    const int oct = (pct > W_ - 1) ? 2 * (W_ - 1) - pct : pct;
    const bool lo32 = lane < 32;

    // precomputed ds_bpermute byte addresses
    const int A_dn  = ((lane + 31) & 63) << 2;     // S[lane+31]    (used lanes <= 32)
    const int A_u33 = ((lane - 33) & 63) << 2;     // tail-Sx  prefix (lanes >= 33)
    const int A_u1  = ((lane - 1)  & 63) << 2;     // tail-Sx2 prefix (lanes >= 33)

    auto rowbase = [&](int p) {
        int r = row0 + p - PD_;
        r = (r < 0) ? -r : ((r > H_ - 1) ? 2 * (H_ - 1) - r : r);
        return src + (size_t)r * W_;
    };

    // 4-deep prefetch ring for the new-row stream
    float gr[4], gtr[4];
#pragma unroll
    for (int p = 0; p < 4; ++p) {
        const float* rp = rowbase(p);
        gr[p]  = rp[ocm];
        gtr[p] = rp[oct];
    }

    // 32-deep packed bf16 history (static idx only) + vertical rolling sums
    uint32_t hist[32];
    float vmg = 0.f, vmq = 0.f, vt = 0.f;

    // prologue: padded rows 0..30 -> accumulate only, NO scans
#pragma unroll
    for (int p = 0; p < 31; ++p) {
        float g = gr[p & 3], gt = gtr[p & 3];
        {   const float* rp = rowbase(p + 4);      // max 34 < NROWS, no clamp
            gr[p & 3]  = rp[ocm];
            gtr[p & 3] = rp[oct];
        }
        uint32_t rg  = rne_bf16_hi(g);
        uint32_t rgt = rne_bf16_hi(gt);
        hist[p] = rg | (rgt >> 16);
        float fg  = __uint_as_float(rg);
        float fgt = __uint_as_float(rgt);
        vmg += fg;
        vmq += fg * fg;
        vt  += lo32 ? fgt : fgt * fgt;
    }
    hist[31] = 0u;                                 // step i=0 subtracts zero

    // x-center prefetch ring: rows 0..3
    float xr[4];
#pragma unroll
    for (int k = 0; k < 4; ++k) xr[k] = xp[(size_t)k * W_];

    // main: output rows 0..63, two 32-step blocks (slots static in k:
    // ib ≡ 0 mod 32 so (i-1)&31 == (k+31)&31, (i+31)&3 == (k+3)&3, i&3 == k&3)
    for (int pb = 0; pb < 2; ++pb) {
        const int ib = pb * 32;
#pragma unroll
        for (int k = 0; k < 32; ++k) {
            const int i = ib + k;                  // runtime-uniform row idx
            // new padded row p = i+31 from ring; prefetch p+4
            float g = gr[(k + 3) & 3], gt = gtr[(k + 3) & 3];
            {   int pn = i + 35; if (pn > NROWS - 1) pn = NROWS - 1;
                const float* rp = rowbase(pn);
                gr[(k + 3) & 3]  = rp[ocm];
                gtr[(k + 3) & 3] = rp[oct];
            }
            // center x for this output row; prefetch row i+4
            float xv = xr[k & 3];
            {   int xn = i + 4; if (xn > TY - 1) xn = TY - 1;
                xr[k & 3] = xp[(size_t)xn * W_];
            }

            // bf16-round, update rolling vertical sums with exact cancellation
            uint32_t rg  = rne_bf16_hi(g);
            uint32_t rgt = rne_bf16_hi(gt);
            uint32_t old = hist[(k + 31) & 31];    // row i-1 leaves the window
            hist[(k + 31) & 31] = rg | (rgt >> 16);
            float fg  = __uint_as_float(rg);
            float fgt = __uint_as_float(rgt);
            float og  = __uint_as_float(old & 0xffff0000u);
            float ogt = __uint_as_float(old << 16);
            vmg += fg - og;
            vmq += fg * fg;
            vmq -= og * og;
            float dtl = fgt - ogt;
            float dth = fgt * fgt - ogt * ogt;
            vt += lo32 ? dtl : dth;

            // horizontal 32-window on vertical sums: hsum = S[c+31] - S[c-1]
            float sag = wave_incl_scan(vmg);
            float saq = wave_incl_scan(vmq);
            float sbt = half_scan(vt);
            float sa63g = bcast63(sag), sa63q = bcast63(saq);
            float dng = bperm(A_dn, sag);          // S[lane+31], lanes <= 32
            float dnq = bperm(A_dn, saq);
            float ubg = bperm(A_u33, sbt);         // tail-Sx prefix, lanes >= 33
            float ubq = bperm(A_u1,  sbt);         // tail-Sx2 prefix, lanes >= 33
            float slog = sag - vmg, sloq = saq - vmq;
            float shig = (lane <= 32) ? dng : (sa63g + ubg);
            float shiq = (lane <= 32) ? dnq : (sa63q + ubq);
            float sg = shig - slog;                // 32x32 box sum of x
            float sq = shiq - sloq;                // 32x32 box sum of x^2

            float mg = sg * (1.f / 1024.f);
            float mq = sq * (1.f / 1024.f);
            float sd = sqrtf(fabsf(mq - mg * mg)) + 1e-10f;
            float r  = __fdividef(xv - mg, sd);
            r = fminf(fmaxf(r, -6.f), 6.f);
            dst[(size_t)i * W_] = r;
        }
    }
}

extern "C" void kernel_launch(void* const* d_in, const int* in_sizes, int n_in,
                              void* d_out, int out_size, void* d_ws, size_t ws_size,
                              hipStream_t stream) {
    (void)in_sizes; (void)n_in; (void)d_ws; (void)ws_size; (void)out_size;
    const float* x = (const float*)d_in[0];
    float* o = (float*)d_out;
    dim3 grid(W_ / 256, H_ / TY, NIMG);   // 2 x 8 x 96 = 1536 blocks
    localnorm_kernel<<<grid, dim3(256), 0, stream>>>(x, o);
}

// Round 4
// 215.727 us; speedup vs baseline: 1.7619x; 1.0222x over previous
//
#include <hip/hip_runtime.h>
#include <cstddef>
#include <cstdint>

#define H_    512
#define W_    512
#define NIMG  96           // 32 batch * 3 channels
#define PD_   16           // pad = KS/2
#define TY    64           // output rows per band
#define NROWS (TY + 31)    // 95 padded rows per band

// one DPP scan step: x += dpp_shifted(x); out-of-range lanes contribute 0
template <int CTRL, int RMASK>
__device__ __forceinline__ float dpp_add(float x) {
    int t = __builtin_amdgcn_update_dpp(0, __float_as_int(x), CTRL, RMASK, 0xf, true);
    return x + __int_as_float(t);
}

// wave64 inclusive prefix sum, pure VALU (6 dpp-adds)
__device__ __forceinline__ float wave_incl_scan(float x) {
    x = dpp_add<0x111, 0xf>(x);   // row_shr:1
    x = dpp_add<0x112, 0xf>(x);   // row_shr:2
    x = dpp_add<0x114, 0xf>(x);   // row_shr:4
    x = dpp_add<0x118, 0xf>(x);   // row_shr:8
    x = dpp_add<0x142, 0xa>(x);   // row_bcast:15 -> rows 1,3
    x = dpp_add<0x143, 0xc>(x);   // row_bcast:31 -> rows 2,3
    return x;
}

// TWO independent 32-lane inclusive scans (lanes 0-31 | 32-63), 5 dpp-adds.
// lo half scans tail-Sx, hi half scans tail-Sx^2 in ONE pass.
__device__ __forceinline__ float half_scan(float x) {
    x = dpp_add<0x111, 0xf>(x);
    x = dpp_add<0x112, 0xf>(x);
    x = dpp_add<0x114, 0xf>(x);
    x = dpp_add<0x118, 0xf>(x);
    x = dpp_add<0x142, 0xa>(x);   // row_bcast:15 within each 32-half only
    return x;
}

__device__ __forceinline__ float bcast63(float x) {
    return __int_as_float(__builtin_amdgcn_readlane(__float_as_int(x), 63));
}
__device__ __forceinline__ float bperm(int addr, float v) {
    return __int_as_float(__builtin_amdgcn_ds_bpermute(addr, __float_as_int(v)));
}

// HW packed f32->bf16 RNE convert: ONE instruction replaces ~10 bit-math ops.
// Result: low16 = bf16(a), high16 = bf16(b). Same RNE rounding as the manual
// path (round-3 verified absmax 0.03125), so numerics are unchanged.
__device__ __forceinline__ uint32_t cvt_pk_bf16(float a, float b) {
    uint32_t r;
    asm("v_cvt_pk_bf16_f32 %0, %1, %2" : "=v"(r) : "v"(a), "v"(b));
    return r;
}

// VERTICAL-FIRST localnorm, register history at packed bf16:
// each lane keeps rolling vertical sums of its padded column (main + packed
// tail). The 32-deep subtract history is ONE dword/slot: bf16(gt)|bf16(g).
// Added and subtracted values are the SAME rounded values -> exact rolling
// cancellation, no drift. Center x is f32 via a 4-deep prefetched global
// re-read ring (L2-warm). 3 loads/step, all consumed >=4 steps after issue.
// No LDS, no barriers -> block size is a pure dispatch granule: 2-wave
// blocks give 12 blocks/CU (24 waves/CU) for DPP/bperm latency hiding.
__global__ void __launch_bounds__(128, 6)
localnorm_kernel(const float* __restrict__ xin, float* __restrict__ out)
{
    const int tid  = threadIdx.x;
    const int lane = tid & 63;
    const int wv   = tid >> 6;

    const int c0   = blockIdx.x * 128 + wv * 64;  // wave's first output col
    const int row0 = blockIdx.y * TY;
    const int img  = blockIdx.z;

    const float* __restrict__ src = xin + (size_t)img * (H_ * W_);
    float* __restrict__ dst = out + (size_t)img * (H_ * W_) + (size_t)row0 * W_ + c0 + lane;
    const float* __restrict__ xp = src + (size_t)row0 * W_ + c0 + lane;  // x reload base

    // padded col -> reflected original col (row-invariant)
    int pcm = c0 - PD_ + lane;                     // main: padded idx = lane
    const int ocm = (pcm < 0) ? -pcm : ((pcm > W_ - 1) ? 2 * (W_ - 1) - pcm : pcm);
    int pct = c0 - PD_ + 64 + (lane & 31);         // tail: both halves load same col
    const int oct = (pct > W_ - 1) ? 2 * (W_ - 1) - pct : pct;
    const bool lo32 = lane < 32;

    // precomputed ds_bpermute byte addresses
    const int A_dn  = ((lane + 31) & 63) << 2;     // S[lane+31]    (used lanes <= 32)
    const int A_u33 = ((lane - 33) & 63) << 2;     // tail-Sx  prefix (lanes >= 33)
    const int A_u1  = ((lane - 1)  & 63) << 2;     // tail-Sx2 prefix (lanes >= 33)

    auto rowbase = [&](int p) {
        int r = row0 + p - PD_;
        r = (r < 0) ? -r : ((r > H_ - 1) ? 2 * (H_ - 1) - r : r);
        return src + (size_t)r * W_;
    };

    // 4-deep prefetch ring for the new-row stream
    float gr[4], gtr[4];
#pragma unroll
    for (int p = 0; p < 4; ++p) {
        const float* rp = rowbase(p);
        gr[p]  = rp[ocm];
        gtr[p] = rp[oct];
    }

    // 32-deep packed bf16 history (static idx only) + vertical rolling sums
    uint32_t hist[32];
    float vmg = 0.f, vmq = 0.f, vt = 0.f;

    // prologue: padded rows 0..30 -> accumulate only, NO scans
#pragma unroll
    for (int p = 0; p < 31; ++p) {
        float g = gr[p & 3], gt = gtr[p & 3];
        {   const float* rp = rowbase(p + 4);      // max 34 < NROWS, no clamp
            gr[p & 3]  = rp[ocm];
            gtr[p & 3] = rp[oct];
        }
        uint32_t pk = cvt_pk_bf16(g, gt);          // lo16=bf16(g), hi16=bf16(gt)
        hist[p] = pk;
        float fg  = __uint_as_float(pk << 16);
        float fgt = __uint_as_float(pk & 0xffff0000u);
        vmg += fg;
        vmq += fg * fg;
        vt  += lo32 ? fgt : fgt * fgt;
    }
    hist[31] = 0u;                                 // step i=0 subtracts zero

    // x-center prefetch ring: rows 0..3
    float xr[4];
#pragma unroll
    for (int k = 0; k < 4; ++k) xr[k] = xp[(size_t)k * W_];

    // main: output rows 0..63, two 32-step blocks (slots static in k:
    // ib ≡ 0 mod 32 so (i-1)&31 == (k+31)&31, ring slots likewise)
    for (int pb = 0; pb < 2; ++pb) {
        const int ib = pb * 32;
#pragma unroll
        for (int k = 0; k < 32; ++k) {
            const int i = ib + k;                  // runtime-uniform row idx
            // new padded row p = i+31 from ring; prefetch p+4
            float g = gr[(k + 3) & 3], gt = gtr[(k + 3) & 3];
            {   int pn = i + 35; if (pn > NROWS - 1) pn = NROWS - 1;
                const float* rp = rowbase(pn);
                gr[(k + 3) & 3]  = rp[ocm];
                gtr[(k + 3) & 3] = rp[oct];
            }
            // center x for this output row; prefetch row i+4
            float xv = xr[k & 3];
            {   int xn = i + 4; if (xn > TY - 1) xn = TY - 1;
                xr[k & 3] = xp[(size_t)xn * W_];
            }

            // bf16-pack (1 instr), update rolling sums with exact cancellation
            uint32_t pk  = cvt_pk_bf16(g, gt);
            uint32_t old = hist[(k + 31) & 31];    // row i-1 leaves the window
            hist[(k + 31) & 31] = pk;
            float fg  = __uint_as_float(pk << 16);
            float fgt = __uint_as_float(pk & 0xffff0000u);
            float og  = __uint_as_float(old << 16);
            float ogt = __uint_as_float(old & 0xffff0000u);
            vmg += fg - og;
            vmq += fg * fg;
            vmq -= og * og;
            float dtl = fgt - ogt;
            float dth = fgt * fgt - ogt * ogt;
            vt += lo32 ? dtl : dth;

            // horizontal 32-window on vertical sums: hsum = S[c+31] - S[c-1]
            float sag = wave_incl_scan(vmg);
            float saq = wave_incl_scan(vmq);
            float sbt = half_scan(vt);
            float sa63g = bcast63(sag), sa63q = bcast63(saq);
            float dng = bperm(A_dn, sag);          // S[lane+31], lanes <= 32
            float dnq = bperm(A_dn, saq);
            float ubg = bperm(A_u33, sbt);         // tail-Sx prefix, lanes >= 33
            float ubq = bperm(A_u1,  sbt);         // tail-Sx2 prefix, lanes >= 33
            float slog = sag - vmg, sloq = saq - vmq;
            float shig = (lane <= 32) ? dng : (sa63g + ubg);
            float shiq = (lane <= 32) ? dnq : (sa63q + ubq);
            float sg = shig - slog;                // 32x32 box sum of x
            float sq = shiq - sloq;                // 32x32 box sum of x^2

            float mg = sg * (1.f / 1024.f);
            float mq = sq * (1.f / 1024.f);
            float sd = sqrtf(fabsf(mq - mg * mg)) + 1e-10f;
            float r  = __fdividef(xv - mg, sd);
            r = fminf(fmaxf(r, -6.f), 6.f);
            dst[(size_t)i * W_] = r;
        }
    }
}

extern "C" void kernel_launch(void* const* d_in, const int* in_sizes, int n_in,
                              void* d_out, int out_size, void* d_ws, size_t ws_size,
                              hipStream_t stream) {
    (void)in_sizes; (void)n_in; (void)d_ws; (void)ws_size; (void)out_size;
    const float* x = (const float*)d_in[0];
    float* o = (float*)d_out;
    dim3 grid(W_ / 128, H_ / TY, NIMG);   // 4 x 8 x 96 = 3072 two-wave blocks, 12/CU
    localnorm_kernel<<<grid, dim3(128), 0, stream>>>(x, o);
}